// Round 3
// baseline (1705.137 us; speedup 1.0000x reference)
//
#include <hip/hip_runtime.h>

#define D_DIM 128

typedef float f2_t __attribute__((ext_vector_type(2)));

// ---------------------------------------------------------------------------
// K1: histogram of segment ids. int4-vectorized idx reads.
// ---------------------------------------------------------------------------
__global__ __launch_bounds__(256) void hist_kernel(
    const int4* __restrict__ idx4, int* __restrict__ cnt, int n4) {
  int stride = gridDim.x * blockDim.x;
  for (int i = blockIdx.x * blockDim.x + threadIdx.x; i < n4; i += stride) {
    int4 v = idx4[i];
    atomicAdd(&cnt[v.x], 1);
    atomicAdd(&cnt[v.y], 1);
    atomicAdd(&cnt[v.z], 1);
    atomicAdd(&cnt[v.w], 1);
  }
}

// ---------------------------------------------------------------------------
// K2: hierarchical exclusive scan of cnt[S] (65536 -> 256 blocks of 256).
// ---------------------------------------------------------------------------
__global__ __launch_bounds__(256) void scan_local_kernel(
    int* data, int* sums, int S) {
  __shared__ int sd[256];
  int t = threadIdx.x;
  int i = blockIdx.x * 256 + t;
  int v = (i < S) ? data[i] : 0;
  sd[t] = v;
  __syncthreads();
  for (int off = 1; off < 256; off <<= 1) {
    int u = (t >= off) ? sd[t - off] : 0;
    __syncthreads();
    sd[t] += u;
    __syncthreads();
  }
  if (i < S) data[i] = sd[t] - v;
  if (t == 255) sums[blockIdx.x] = sd[255];
}

__global__ __launch_bounds__(256) void scan_sums_kernel(int* sums, int nb) {
  __shared__ int sd[256];
  int t = threadIdx.x;
  int v = (t < nb) ? sums[t] : 0;
  sd[t] = v;
  __syncthreads();
  for (int off = 1; off < 256; off <<= 1) {
    int u = (t >= off) ? sd[t - off] : 0;
    __syncthreads();
    sd[t] += u;
    __syncthreads();
  }
  if (t < nb) sums[t] = sd[t] - v;
}

__global__ __launch_bounds__(256) void scan_add_kernel(
    int* data, const int* __restrict__ sums, int S) {
  int i = blockIdx.x * 256 + threadIdx.x;
  if (i < S) data[i] += sums[blockIdx.x];
}

// ---------------------------------------------------------------------------
// K3: scatter row ids into segment-sorted order (bump cnt in place).
// ---------------------------------------------------------------------------
__global__ __launch_bounds__(256) void scatter_idx_kernel(
    const int4* __restrict__ idx4, int* cnt, int* __restrict__ rowids, int n4) {
  int stride = gridDim.x * blockDim.x;
  for (int i = blockIdx.x * blockDim.x + threadIdx.x; i < n4; i += stride) {
    int4 v = idx4[i];
    int r = i * 4;
    rowids[atomicAdd(&cnt[v.x], 1)] = r;
    rowids[atomicAdd(&cnt[v.y], 1)] = r + 1;
    rowids[atomicAdd(&cnt[v.z], 1)] = r + 2;
    rowids[atomicAdd(&cnt[v.w], 1)] = r + 3;
  }
}

// ---------------------------------------------------------------------------
// K4: fused gather-reduce + linear transform.
// block = 1024 (16 waves); LDS 66 KB -> 2 blocks/CU -> 32 waves/CU (max).
// Unroll 8 rows -> 8 outstanding 512B global reads per wave (4 KB in flight).
// x read nontemporally (single-use 2 GiB stream; keep L2/L3 for rowids/W).
// ---------------------------------------------------------------------------
__global__ __launch_bounds__(1024) void gather_transform_kernel(
    const float* __restrict__ x,
    const int* __restrict__ rowids,
    const int* __restrict__ cnt,      // post-scatter: cnt[s] = end of seg s
    const float* __restrict__ W,      // [128,128] row-major [out][in]
    const float* __restrict__ b,      // [128]
    float* __restrict__ out,          // [S,128]
    int S) {
  __shared__ float Wt[D_DIM][D_DIM + 1];  // Wt[d][j] = W[j][d]
  int t = threadIdx.x;
  for (int f = t; f < D_DIM * D_DIM; f += 1024)
    Wt[f & (D_DIM - 1)][f >> 7] = W[f];
  __syncthreads();

  int lane = t & 63;
  int wv = t >> 6;                       // 0..15
  float2 bb = *reinterpret_cast<const float2*>(&b[2 * lane]);
  int nW = gridDim.x * 16;

  for (int s = blockIdx.x * 16 + wv; s < S; s += nW) {
    int start = (s == 0) ? 0 : cnt[s - 1];
    int end = cnt[s];
    float ax = 0.f, ay = 0.f;

    for (int base = start; base < end; base += 64) {
      int m = end - base;
      int rid = 0;
      if (lane < m) rid = rowids[base + lane];
      int c = m < 64 ? m : 64;
      int j = 0;
      for (; j + 8 <= c; j += 8) {
        int r0 = __shfl(rid, j);
        int r1 = __shfl(rid, j + 1);
        int r2 = __shfl(rid, j + 2);
        int r3 = __shfl(rid, j + 3);
        int r4 = __shfl(rid, j + 4);
        int r5 = __shfl(rid, j + 5);
        int r6 = __shfl(rid, j + 6);
        int r7 = __shfl(rid, j + 7);
        f2_t v0 = __builtin_nontemporal_load((const f2_t*)(x + (((long long)r0) << 7) + 2 * lane));
        f2_t v1 = __builtin_nontemporal_load((const f2_t*)(x + (((long long)r1) << 7) + 2 * lane));
        f2_t v2 = __builtin_nontemporal_load((const f2_t*)(x + (((long long)r2) << 7) + 2 * lane));
        f2_t v3 = __builtin_nontemporal_load((const f2_t*)(x + (((long long)r3) << 7) + 2 * lane));
        f2_t v4 = __builtin_nontemporal_load((const f2_t*)(x + (((long long)r4) << 7) + 2 * lane));
        f2_t v5 = __builtin_nontemporal_load((const f2_t*)(x + (((long long)r5) << 7) + 2 * lane));
        f2_t v6 = __builtin_nontemporal_load((const f2_t*)(x + (((long long)r6) << 7) + 2 * lane));
        f2_t v7 = __builtin_nontemporal_load((const f2_t*)(x + (((long long)r7) << 7) + 2 * lane));
        ax += v0.x + v1.x + v2.x + v3.x + v4.x + v5.x + v6.x + v7.x;
        ay += v0.y + v1.y + v2.y + v3.y + v4.y + v5.y + v6.y + v7.y;
      }
      for (; j < c; ++j) {
        int r = __shfl(rid, j);
        f2_t v = __builtin_nontemporal_load((const f2_t*)(x + (((long long)r) << 7) + 2 * lane));
        ax += v.x;
        ay += v.y;
      }
    }

    // out[s][j] = b[j] + sum_d pooled[d] * W[j][d]
    float ox = bb.x, oy = bb.y;
#pragma unroll
    for (int k = 0; k < 64; ++k) {
      float p0 = __shfl(ax, k);
      float p1 = __shfl(ay, k);
      float2 w0 = *reinterpret_cast<const float2*>(&Wt[2 * k][2 * lane]);
      float2 w1 = *reinterpret_cast<const float2*>(&Wt[2 * k + 1][2 * lane]);
      ox += p0 * w0.x + p1 * w1.x;
      oy += p0 * w0.y + p1 * w1.y;
    }
    *reinterpret_cast<float2*>(&out[(long long)s * D_DIM + 2 * lane]) =
        make_float2(ox, oy);
  }
}

extern "C" void kernel_launch(void* const* d_in, const int* in_sizes, int n_in,
                              void* d_out, int out_size, void* d_ws, size_t ws_size,
                              hipStream_t stream) {
  const float* x = (const float*)d_in[0];
  const int* idx = (const int*)d_in[1];
  const float* W = (const float*)d_in[3];
  const float* b = (const float*)d_in[4];
  float* out = (float*)d_out;

  int N = in_sizes[0] / D_DIM;
  int S = out_size / D_DIM;
  int nb = (S + 255) / 256;

  // ws layout: cnt[S] | sums[256] | rowids[N]
  int* cnt = (int*)d_ws;
  int* sums = cnt + S;
  int* rowids = sums + 256;

  hipMemsetAsync(d_ws, 0, (size_t)(S + 256) * sizeof(int), stream);

  int n4 = N / 4;
  hist_kernel<<<1024, 256, 0, stream>>>((const int4*)idx, cnt, n4);
  scan_local_kernel<<<nb, 256, 0, stream>>>(cnt, sums, S);
  scan_sums_kernel<<<1, 256, 0, stream>>>(sums, nb);
  scan_add_kernel<<<nb, 256, 0, stream>>>(cnt, sums, S);
  scatter_idx_kernel<<<1024, 256, 0, stream>>>((const int4*)idx, cnt, rowids, n4);
  gather_transform_kernel<<<1024, 1024, 0, stream>>>(x, rowids, cnt, W, b, out, S);
}

// Round 4
// 1226.630 us; speedup vs baseline: 1.3901x; 1.3901x over previous
//
#include <hip/hip_runtime.h>

#define D_DIM 128

typedef float f4_t __attribute__((ext_vector_type(4)));

// ---------------------------------------------------------------------------
// K1: histogram of segment ids.
// ---------------------------------------------------------------------------
__global__ __launch_bounds__(256) void hist_kernel(
    const int* __restrict__ idx, int* __restrict__ cnt, int n) {
  int stride = gridDim.x * blockDim.x;
  for (int i = blockIdx.x * blockDim.x + threadIdx.x; i < n; i += stride)
    atomicAdd(&cnt[idx[i]], 1);
}

// ---------------------------------------------------------------------------
// K2: hierarchical exclusive scan of cnt[S] (65536 -> 256 blocks of 256).
// ---------------------------------------------------------------------------
__global__ __launch_bounds__(256) void scan_local_kernel(
    int* data, int* sums, int S) {
  __shared__ int sd[256];
  int t = threadIdx.x;
  int i = blockIdx.x * 256 + t;
  int v = (i < S) ? data[i] : 0;
  sd[t] = v;
  __syncthreads();
  for (int off = 1; off < 256; off <<= 1) {
    int u = (t >= off) ? sd[t - off] : 0;
    __syncthreads();
    sd[t] += u;
    __syncthreads();
  }
  if (i < S) data[i] = sd[t] - v;
  if (t == 255) sums[blockIdx.x] = sd[255];
}

__global__ __launch_bounds__(256) void scan_sums_kernel(int* sums, int nb) {
  __shared__ int sd[256];
  int t = threadIdx.x;
  int v = (t < nb) ? sums[t] : 0;
  sd[t] = v;
  __syncthreads();
  for (int off = 1; off < 256; off <<= 1) {
    int u = (t >= off) ? sd[t - off] : 0;
    __syncthreads();
    sd[t] += u;
    __syncthreads();
  }
  if (t < nb) sums[t] = sd[t] - v;
}

__global__ __launch_bounds__(256) void scan_add_kernel(
    int* data, const int* __restrict__ sums, int S) {
  int i = blockIdx.x * 256 + threadIdx.x;
  if (i < S) data[i] += sums[blockIdx.x];
}

// ---------------------------------------------------------------------------
// K3: scatter row ids into segment-sorted order (bump cnt in place).
// ---------------------------------------------------------------------------
__global__ __launch_bounds__(256) void scatter_idx_kernel(
    const int* __restrict__ idx, int* cnt, int* __restrict__ rowids, int n) {
  int stride = gridDim.x * blockDim.x;
  for (int i = blockIdx.x * blockDim.x + threadIdx.x; i < n; i += stride) {
    int pos = atomicAdd(&cnt[idx[i]], 1);
    rowids[pos] = i;
  }
}

// ---------------------------------------------------------------------------
// K4a: gather-reduce. NO LDS -> occupancy limited only by VGPRs.
// One wave per segment. float4 per lane over HALF-waves: lanes 0..31 read row
// A (32 x 16B = 512B contiguous), lanes 32..63 read row B. One instruction
// fetches 2 rows; unroll 8 -> 16 rows / 8 KB in flight per wave.
// __launch_bounds__(256,6) caps VGPR at ~84 -> 24 waves/CU.
// Final half-combine via shfl(lane^32); lanes 0..31 write pooled as float4.
// ---------------------------------------------------------------------------
__global__ __launch_bounds__(256, 6) void gather_reduce_kernel(
    const float* __restrict__ x,
    const int* __restrict__ rowids,
    const int* __restrict__ cnt,      // cnt[s] = end offset of segment s
    float* __restrict__ pooled,       // [S,128]
    int S) {
  int lane = threadIdx.x & 63;
  int wv = threadIdx.x >> 6;          // 0..3
  int half = lane >> 5;               // which row of the pair this lane reads
  int coff = (lane & 31) << 2;        // float column (x4 floats = 16B)
  int nW = gridDim.x * 4;

  for (int s = blockIdx.x * 4 + wv; s < S; s += nW) {
    int start = (s == 0) ? 0 : cnt[s - 1];
    int end = cnt[s];
    f4_t acc = {0.f, 0.f, 0.f, 0.f};

    int base = start;
    while (base < end) {
      int m = end - base;
      int c = m < 64 ? m : 64;
      int ridv = (lane < c) ? rowids[base + lane] : 0;
      int j = 0;
      for (; j + 16 <= c; j += 16) {
        f4_t v0, v1, v2, v3, v4, v5, v6, v7;
        {
          int rA, rB, r;
          rA = __shfl(ridv, j + 0);  rB = __shfl(ridv, j + 1);
          r = half ? rB : rA;
          v0 = *reinterpret_cast<const f4_t*>(x + ((long long)r << 7) + coff);
          rA = __shfl(ridv, j + 2);  rB = __shfl(ridv, j + 3);
          r = half ? rB : rA;
          v1 = *reinterpret_cast<const f4_t*>(x + ((long long)r << 7) + coff);
          rA = __shfl(ridv, j + 4);  rB = __shfl(ridv, j + 5);
          r = half ? rB : rA;
          v2 = *reinterpret_cast<const f4_t*>(x + ((long long)r << 7) + coff);
          rA = __shfl(ridv, j + 6);  rB = __shfl(ridv, j + 7);
          r = half ? rB : rA;
          v3 = *reinterpret_cast<const f4_t*>(x + ((long long)r << 7) + coff);
          rA = __shfl(ridv, j + 8);  rB = __shfl(ridv, j + 9);
          r = half ? rB : rA;
          v4 = *reinterpret_cast<const f4_t*>(x + ((long long)r << 7) + coff);
          rA = __shfl(ridv, j + 10); rB = __shfl(ridv, j + 11);
          r = half ? rB : rA;
          v5 = *reinterpret_cast<const f4_t*>(x + ((long long)r << 7) + coff);
          rA = __shfl(ridv, j + 12); rB = __shfl(ridv, j + 13);
          r = half ? rB : rA;
          v6 = *reinterpret_cast<const f4_t*>(x + ((long long)r << 7) + coff);
          rA = __shfl(ridv, j + 14); rB = __shfl(ridv, j + 15);
          r = half ? rB : rA;
          v7 = *reinterpret_cast<const f4_t*>(x + ((long long)r << 7) + coff);
        }
        acc += v0; acc += v1; acc += v2; acc += v3;
        acc += v4; acc += v5; acc += v6; acc += v7;
      }
      for (; j + 2 <= c; j += 2) {
        int rA = __shfl(ridv, j);
        int rB = __shfl(ridv, j + 1);
        int r = half ? rB : rA;
        f4_t v = *reinterpret_cast<const f4_t*>(x + ((long long)r << 7) + coff);
        acc += v;
      }
      if (j < c) {  // odd final row: half 0 only
        int rA = __shfl(ridv, j);
        if (!half) {
          f4_t v = *reinterpret_cast<const f4_t*>(x + ((long long)rA << 7) + coff);
          acc += v;
        }
      }
      base += c;
    }

    // combine the two halves (lane i <-> lane i+32 hold same columns)
    f4_t other;
    other.x = __shfl(acc.x, lane ^ 32);
    other.y = __shfl(acc.y, lane ^ 32);
    other.z = __shfl(acc.z, lane ^ 32);
    other.w = __shfl(acc.w, lane ^ 32);
    acc += other;
    if (!half) {
      *reinterpret_cast<f4_t*>(pooled + ((long long)s << 7) + coff) = acc;
    }
  }
}

// ---------------------------------------------------------------------------
// K4b: transform. out[s][j] = b[j] + sum_d pooled[s][d] * W[j][d].
// Wt (transposed W) in LDS; one wave per 2 rows (2 independent FMA chains).
// ---------------------------------------------------------------------------
__global__ __launch_bounds__(256) void transform_kernel(
    const float* __restrict__ pooled,
    const float* __restrict__ W,      // [128,128] row-major [out][in]
    const float* __restrict__ b,
    float* __restrict__ out, int S) {
  __shared__ float Wt[D_DIM][D_DIM + 1];  // Wt[d][j] = W[j][d]
  int t = threadIdx.x;
  for (int f = t; f < D_DIM * D_DIM; f += 256)
    Wt[f & (D_DIM - 1)][f >> 7] = W[f];
  __syncthreads();

  int lane = t & 63;
  int wv = t >> 6;
  float2 bb = *reinterpret_cast<const float2*>(&b[2 * lane]);
  int stride = gridDim.x * 4 * 2;

  for (int s0 = (blockIdx.x * 4 + wv) * 2; s0 < S; s0 += stride) {
    float2 rv0 = *reinterpret_cast<const float2*>(&pooled[(long long)s0 * D_DIM + 2 * lane]);
    bool has1 = (s0 + 1) < S;
    float2 rv1 = has1
        ? *reinterpret_cast<const float2*>(&pooled[(long long)(s0 + 1) * D_DIM + 2 * lane])
        : make_float2(0.f, 0.f);
    float o0x = bb.x, o0y = bb.y, o1x = bb.x, o1y = bb.y;
#pragma unroll
    for (int k = 0; k < 64; ++k) {
      float p00 = __shfl(rv0.x, k);
      float p01 = __shfl(rv0.y, k);
      float p10 = __shfl(rv1.x, k);
      float p11 = __shfl(rv1.y, k);
      float2 w0 = *reinterpret_cast<const float2*>(&Wt[2 * k][2 * lane]);
      float2 w1 = *reinterpret_cast<const float2*>(&Wt[2 * k + 1][2 * lane]);
      o0x += p00 * w0.x + p01 * w1.x;
      o0y += p00 * w0.y + p01 * w1.y;
      o1x += p10 * w0.x + p11 * w1.x;
      o1y += p10 * w0.y + p11 * w1.y;
    }
    *reinterpret_cast<float2*>(&out[(long long)s0 * D_DIM + 2 * lane]) =
        make_float2(o0x, o0y);
    if (has1)
      *reinterpret_cast<float2*>(&out[(long long)(s0 + 1) * D_DIM + 2 * lane]) =
          make_float2(o1x, o1y);
  }
}

extern "C" void kernel_launch(void* const* d_in, const int* in_sizes, int n_in,
                              void* d_out, int out_size, void* d_ws, size_t ws_size,
                              hipStream_t stream) {
  const float* x = (const float*)d_in[0];
  const int* idx = (const int*)d_in[1];
  const float* W = (const float*)d_in[3];
  const float* b = (const float*)d_in[4];
  float* out = (float*)d_out;

  int N = in_sizes[0] / D_DIM;
  int S = out_size / D_DIM;
  int nb = (S + 255) / 256;

  // ws layout: cnt[S] | sums[256] | rowids[N] | pooled[S*128]
  int* cnt = (int*)d_ws;
  int* sums = cnt + S;
  int* rowids = sums + 256;
  float* pooled = (float*)(rowids + N);

  hipMemsetAsync(d_ws, 0, (size_t)(S + 256) * sizeof(int), stream);

  hist_kernel<<<4096, 256, 0, stream>>>(idx, cnt, N);
  scan_local_kernel<<<nb, 256, 0, stream>>>(cnt, sums, S);
  scan_sums_kernel<<<1, 256, 0, stream>>>(sums, nb);
  scan_add_kernel<<<nb, 256, 0, stream>>>(cnt, sums, S);
  scatter_idx_kernel<<<4096, 256, 0, stream>>>(idx, cnt, rowids, N);
  gather_reduce_kernel<<<4096, 256, 0, stream>>>(x, rowids, cnt, pooled, S);
  transform_kernel<<<2048, 256, 0, stream>>>(pooled, W, b, out, S);
}

// Round 5
// 1068.606 us; speedup vs baseline: 1.5957x; 1.1479x over previous
//
#include <hip/hip_runtime.h>

#define D_DIM 128
#define SLOT_CAP 128

typedef float f4_t __attribute__((ext_vector_type(4)));

// ---------------------------------------------------------------------------
// K1: single-pass scatter into fixed-capacity per-segment slot lists.
// fill[s] counts ALL rows of segment s; rows with pos < SLOT_CAP go to
// slots[s*128+pos], the (astronomically rare) rest to an overflow list that
// a dedicated fixup kernel folds in AFTER the gather (correct for any input).
// ---------------------------------------------------------------------------
__global__ __launch_bounds__(256) void scatter_slots_kernel(
    const int* __restrict__ idx,
    int* __restrict__ fill,         // [S]
    int* __restrict__ slots,        // [S*SLOT_CAP]
    int* __restrict__ ov_count,
    int* __restrict__ ovs, int* __restrict__ ovr,
    int n) {
  int stride = gridDim.x * blockDim.x;
  for (int i = blockIdx.x * blockDim.x + threadIdx.x; i < n; i += stride) {
    int s = idx[i];
    int pos = atomicAdd(&fill[s], 1);
    if (pos < SLOT_CAP) {
      slots[(long long)s * SLOT_CAP + pos] = i;
    } else {
      int o = atomicAdd(ov_count, 1);
      ovs[o] = s;
      ovr[o] = i;
    }
  }
}

// ---------------------------------------------------------------------------
// K2: gather-reduce. One wave owns 4 CONTIGUOUS segments.
// - fill[s0..s0+3] read as one uniform int4 (scalar load)
// - all row-ids staged to LDS up front (2 KB/wave) -> row-id HBM latency is
//   paid once per wave, off the x-load critical path
// - x rows read as float4/lane over half-waves (lanes 0..31 row A, 32..63
//   row B; 1 KB per instruction), 8 pair-loads (16 rows, 8 KB) in flight
// - no global fallback in the hot loop: overflow rows handled by K3
// ---------------------------------------------------------------------------
__global__ __launch_bounds__(256, 6) void gather_reduce_kernel(
    const float* __restrict__ x,
    const int* __restrict__ slots,
    const int* __restrict__ fill,
    float* __restrict__ pooled,      // [S,128]
    int S) {
  __shared__ int ridbuf[4][4 * SLOT_CAP];  // 8 KB
  int t = threadIdx.x;
  int lane = t & 63;
  int wv = t >> 6;
  int half = lane >> 5;
  int coff = (lane & 31) << 2;
  int s0 = (blockIdx.x * 4 + wv) * 4;
  if (s0 >= S) return;

  int c0, c1, c2, c3;
  if (s0 + 3 < S) {
    int4 f = *reinterpret_cast<const int4*>(fill + s0);  // 16B-aligned (s0%4==0)
    c0 = min(f.x, SLOT_CAP); c1 = min(f.y, SLOT_CAP);
    c2 = min(f.z, SLOT_CAP); c3 = min(f.w, SLOT_CAP);
  } else {
    c0 = (s0 + 0 < S) ? min(fill[s0 + 0], SLOT_CAP) : 0;
    c1 = (s0 + 1 < S) ? min(fill[s0 + 1], SLOT_CAP) : 0;
    c2 = (s0 + 2 < S) ? min(fill[s0 + 2], SLOT_CAP) : 0;
    c3 = (s0 + 3 < S) ? min(fill[s0 + 3], SLOT_CAP) : 0;
  }

  // stage the 4 slot lists into LDS (coalesced 4B/lane reads)
#pragma unroll
  for (int g = 0; g < 4; ++g) {
    int c = g == 0 ? c0 : g == 1 ? c1 : g == 2 ? c2 : c3;
    const int* sp = slots + (long long)(s0 + g) * SLOT_CAP;
    if (lane < c) ridbuf[wv][g * SLOT_CAP + lane] = sp[lane];
    if (lane + 64 < c) ridbuf[wv][g * SLOT_CAP + lane + 64] = sp[lane + 64];
  }
  // same-wave ds_write->ds_read ordering handled by compiler (lgkmcnt)

#pragma unroll
  for (int g = 0; g < 4; ++g) {
    int c = g == 0 ? c0 : g == 1 ? c1 : g == 2 ? c2 : c3;
    f4_t acc = {0.f, 0.f, 0.f, 0.f};
    for (int pos = 0; pos < c; pos += 16) {
#pragma unroll
      for (int u = 0; u < 8; ++u) {
        int p = pos + 2 * u + half;
        if (p < c) {
          int r = ridbuf[wv][g * SLOT_CAP + p];
          acc += *reinterpret_cast<const f4_t*>(x + ((long long)r << 7) + coff);
        }
      }
    }
    // cross-half combine (lane i <-> lane i^32 hold the same columns)
    f4_t oth;
    oth.x = __shfl(acc.x, lane ^ 32);
    oth.y = __shfl(acc.y, lane ^ 32);
    oth.z = __shfl(acc.z, lane ^ 32);
    oth.w = __shfl(acc.w, lane ^ 32);
    acc += oth;
    if (!half && s0 + g < S) {
      *reinterpret_cast<f4_t*>(pooled + ((long long)(s0 + g) << 7) + coff) = acc;
    }
  }
}

// ---------------------------------------------------------------------------
// K3: overflow fixup (runs AFTER gather, BEFORE transform -> no races).
// For the benchmark's uniform-random idx, ov_count == 0 and this is a no-op.
// ---------------------------------------------------------------------------
__global__ __launch_bounds__(128) void fixup_kernel(
    const int* __restrict__ ov_count,
    const int* __restrict__ ovs, const int* __restrict__ ovr,
    const float* __restrict__ x,
    float* __restrict__ pooled) {
  int n = *ov_count;
  for (int k = blockIdx.x; k < n; k += gridDim.x) {
    int s = ovs[k];
    long long r = ovr[k];
    int c = threadIdx.x;
    atomicAdd(&pooled[(long long)s * D_DIM + c], x[r * D_DIM + c]);
  }
}

// ---------------------------------------------------------------------------
// K4: transform. out[s][j] = b[j] + sum_d pooled[s][d] * W[j][d].
// Wt (transposed W) in LDS; one wave per 2 rows (2 independent FMA chains).
// ---------------------------------------------------------------------------
__global__ __launch_bounds__(256) void transform_kernel(
    const float* __restrict__ pooled,
    const float* __restrict__ W,      // [128,128] row-major [out][in]
    const float* __restrict__ b,
    float* __restrict__ out, int S) {
  __shared__ float Wt[D_DIM][D_DIM + 1];  // Wt[d][j] = W[j][d]
  int t = threadIdx.x;
  for (int f = t; f < D_DIM * D_DIM; f += 256)
    Wt[f & (D_DIM - 1)][f >> 7] = W[f];
  __syncthreads();

  int lane = t & 63;
  int wv = t >> 6;
  float2 bb = *reinterpret_cast<const float2*>(&b[2 * lane]);
  int stride = gridDim.x * 4 * 2;

  for (int s0 = (blockIdx.x * 4 + wv) * 2; s0 < S; s0 += stride) {
    float2 rv0 = *reinterpret_cast<const float2*>(&pooled[(long long)s0 * D_DIM + 2 * lane]);
    bool has1 = (s0 + 1) < S;
    float2 rv1 = has1
        ? *reinterpret_cast<const float2*>(&pooled[(long long)(s0 + 1) * D_DIM + 2 * lane])
        : make_float2(0.f, 0.f);
    float o0x = bb.x, o0y = bb.y, o1x = bb.x, o1y = bb.y;
#pragma unroll
    for (int k = 0; k < 64; ++k) {
      float p00 = __shfl(rv0.x, k);
      float p01 = __shfl(rv0.y, k);
      float p10 = __shfl(rv1.x, k);
      float p11 = __shfl(rv1.y, k);
      float2 w0 = *reinterpret_cast<const float2*>(&Wt[2 * k][2 * lane]);
      float2 w1 = *reinterpret_cast<const float2*>(&Wt[2 * k + 1][2 * lane]);
      o0x += p00 * w0.x + p01 * w1.x;
      o0y += p00 * w0.y + p01 * w1.y;
      o1x += p10 * w0.x + p11 * w1.x;
      o1y += p10 * w0.y + p11 * w1.y;
    }
    *reinterpret_cast<float2*>(&out[(long long)s0 * D_DIM + 2 * lane]) =
        make_float2(o0x, o0y);
    if (has1)
      *reinterpret_cast<float2*>(&out[(long long)(s0 + 1) * D_DIM + 2 * lane]) =
          make_float2(o1x, o1y);
  }
}

extern "C" void kernel_launch(void* const* d_in, const int* in_sizes, int n_in,
                              void* d_out, int out_size, void* d_ws, size_t ws_size,
                              hipStream_t stream) {
  const float* x = (const float*)d_in[0];
  const int* idx = (const int*)d_in[1];
  const float* W = (const float*)d_in[3];
  const float* b = (const float*)d_in[4];
  float* out = (float*)d_out;

  int N = in_sizes[0] / D_DIM;
  int S = out_size / D_DIM;

  // ws layout: fill[S] | ov_count[4] | slots[S*128] | ovs[N] | ovr[N] | pooled[S*128]
  int* fill = (int*)d_ws;
  int* ov_count = fill + S;
  int* slots = fill + S + 4;
  int* ovs = slots + (long long)S * SLOT_CAP;
  int* ovr = ovs + N;
  float* pooled = (float*)(ovr + N);

  // zero fill + ov_count (contiguous)
  hipMemsetAsync(fill, 0, (size_t)(S + 4) * sizeof(int), stream);

  scatter_slots_kernel<<<4096, 256, 0, stream>>>(idx, fill, slots, ov_count,
                                                 ovs, ovr, N);
  gather_reduce_kernel<<<(S + 15) / 16, 256, 0, stream>>>(x, slots, fill,
                                                          pooled, S);
  fixup_kernel<<<256, 128, 0, stream>>>(ov_count, ovs, ovr, x, pooled);
  transform_kernel<<<2048, 256, 0, stream>>>(pooled, W, b, out, S);
}

// Round 6
// 1014.913 us; speedup vs baseline: 1.6801x; 1.0529x over previous
//
#include <hip/hip_runtime.h>

#define D_DIM 128
#define SLOT_CAP 128

typedef float f4_t __attribute__((ext_vector_type(4)));

__device__ __forceinline__ f4_t nt_load4(const float* p) {
  return __builtin_nontemporal_load(reinterpret_cast<const f4_t*>(p));
}

// ---------------------------------------------------------------------------
// K1: single-pass scatter into fixed-capacity per-segment slot lists.
// int4 idx loads; 4 independent atomics in flight per thread.
// Overflow (pos >= SLOT_CAP) goes to a list folded in by K3 after the gather.
// ---------------------------------------------------------------------------
__global__ __launch_bounds__(256) void scatter_slots_kernel(
    const int4* __restrict__ idx4,
    int* __restrict__ fill,         // [S]
    int* __restrict__ slots,        // [S*SLOT_CAP]
    int* __restrict__ ov_count,
    int* __restrict__ ovs, int* __restrict__ ovr,
    int n4) {
  int stride = gridDim.x * blockDim.x;
  for (int i = blockIdx.x * blockDim.x + threadIdx.x; i < n4; i += stride) {
    int4 v = idx4[i];
    int r = i * 4;
    int p0 = atomicAdd(&fill[v.x], 1);
    int p1 = atomicAdd(&fill[v.y], 1);
    int p2 = atomicAdd(&fill[v.z], 1);
    int p3 = atomicAdd(&fill[v.w], 1);
    if (p0 < SLOT_CAP) slots[v.x * SLOT_CAP + p0] = r;
    else { int o = atomicAdd(ov_count, 1); ovs[o] = v.x; ovr[o] = r; }
    if (p1 < SLOT_CAP) slots[v.y * SLOT_CAP + p1] = r + 1;
    else { int o = atomicAdd(ov_count, 1); ovs[o] = v.y; ovr[o] = r + 1; }
    if (p2 < SLOT_CAP) slots[v.z * SLOT_CAP + p2] = r + 2;
    else { int o = atomicAdd(ov_count, 1); ovs[o] = v.z; ovr[o] = r + 2; }
    if (p3 < SLOT_CAP) slots[v.w * SLOT_CAP + p3] = r + 3;
    else { int o = atomicAdd(ov_count, 1); ovs[o] = v.w; ovr[o] = r + 3; }
  }
}

// ---------------------------------------------------------------------------
// K2: gather-reduce. One wave owns 4 CONTIGUOUS segments.
// - all 512 slot ids staged via 2 UNCONDITIONAL int4 loads per lane
//   (entries past fill[] are garbage but never consumed)
// - per segment: unpredicated full-16-row chunks (no exec-mask overhead),
//   predicated tail chunk only
// - x rows: float4/lane over half-waves (lanes 0..31 row A, 32..63 row B);
//   nontemporal (2 GB read-once stream -> keep L2 for slots/pooled)
// ---------------------------------------------------------------------------
__global__ __launch_bounds__(256, 6) void gather_reduce_kernel(
    const float* __restrict__ x,
    const int* __restrict__ slots,
    const int* __restrict__ fill,
    float* __restrict__ pooled,      // [S,128]
    int S) {
  __shared__ int ridbuf[4][4 * SLOT_CAP];  // 8 KB
  int t = threadIdx.x;
  int lane = t & 63;
  int wv = t >> 6;
  int half = lane >> 5;
  int coff = (lane & 31) << 2;
  int s0 = (blockIdx.x * 4 + wv) * 4;
  if (s0 >= S) return;

  int c0, c1, c2, c3;
  if (s0 + 3 < S) {
    int4 f = *reinterpret_cast<const int4*>(fill + s0);
    c0 = min(f.x, SLOT_CAP); c1 = min(f.y, SLOT_CAP);
    c2 = min(f.z, SLOT_CAP); c3 = min(f.w, SLOT_CAP);
    // stage all 4 slot lists: 512 ints = 128 int4, 2 per lane, unconditional
    int4* rb4 = reinterpret_cast<int4*>(ridbuf[wv]);
    const int4* sp4 = reinterpret_cast<const int4*>(slots) + s0 * (SLOT_CAP / 4);
    rb4[lane] = sp4[lane];
    rb4[lane + 64] = sp4[lane + 64];
  } else {
    c0 = (s0 + 0 < S) ? min(fill[s0 + 0], SLOT_CAP) : 0;
    c1 = (s0 + 1 < S) ? min(fill[s0 + 1], SLOT_CAP) : 0;
    c2 = (s0 + 2 < S) ? min(fill[s0 + 2], SLOT_CAP) : 0;
    c3 = (s0 + 3 < S) ? min(fill[s0 + 3], SLOT_CAP) : 0;
    for (int g = 0; g < 4; ++g) {
      int c = g == 0 ? c0 : g == 1 ? c1 : g == 2 ? c2 : c3;
      if (s0 + g < S) {
        const int* sp = slots + (long long)(s0 + g) * SLOT_CAP;
        if (lane < c) ridbuf[wv][g * SLOT_CAP + lane] = sp[lane];
        if (lane + 64 < c) ridbuf[wv][g * SLOT_CAP + lane + 64] = sp[lane + 64];
      }
    }
  }

#define DO_SEG(G, CG)                                                        \
  {                                                                          \
    f4_t acc = {0.f, 0.f, 0.f, 0.f};                                         \
    int full = CG & ~15;                                                     \
    for (int base = 0; base < full; base += 16) {                            \
      _Pragma("unroll") for (int u = 0; u < 8; ++u) {                        \
        int p = base + 2 * u + half;                                         \
        int r = ridbuf[wv][(G) * SLOT_CAP + p];                              \
        acc += nt_load4(x + ((long long)r << 7) + coff);                     \
      }                                                                      \
    }                                                                        \
    if (full < CG) {                                                         \
      _Pragma("unroll") for (int u = 0; u < 8; ++u) {                        \
        int p = full + 2 * u + half;                                         \
        if (p < CG) {                                                        \
          int r = ridbuf[wv][(G) * SLOT_CAP + p];                            \
          acc += nt_load4(x + ((long long)r << 7) + coff);                   \
        }                                                                    \
      }                                                                      \
    }                                                                        \
    f4_t oth;                                                                \
    oth.x = __shfl(acc.x, lane ^ 32);                                        \
    oth.y = __shfl(acc.y, lane ^ 32);                                        \
    oth.z = __shfl(acc.z, lane ^ 32);                                        \
    oth.w = __shfl(acc.w, lane ^ 32);                                        \
    acc += oth;                                                              \
    if (!half && s0 + (G) < S) {                                             \
      *reinterpret_cast<f4_t*>(pooled + ((long long)(s0 + (G)) << 7) + coff) = acc; \
    }                                                                        \
  }

  DO_SEG(0, c0)
  DO_SEG(1, c1)
  DO_SEG(2, c2)
  DO_SEG(3, c3)
#undef DO_SEG
}

// ---------------------------------------------------------------------------
// K3: overflow fixup (after gather, before transform -> race-free).
// ov_count == 0 for uniform-random idx; correct for any input regardless.
// ---------------------------------------------------------------------------
__global__ __launch_bounds__(128) void fixup_kernel(
    const int* __restrict__ ov_count,
    const int* __restrict__ ovs, const int* __restrict__ ovr,
    const float* __restrict__ x,
    float* __restrict__ pooled) {
  int n = *ov_count;
  for (int k = blockIdx.x; k < n; k += gridDim.x) {
    int s = ovs[k];
    long long r = ovr[k];
    int c = threadIdx.x;
    atomicAdd(&pooled[(long long)s * D_DIM + c], x[r * D_DIM + c]);
  }
}

// ---------------------------------------------------------------------------
// K4: transform. out[s][j] = b[j] + sum_d pooled[s][d] * W[j][d].
// Wt (transposed W) in LDS; one wave per 2 rows (2 independent FMA chains).
// ---------------------------------------------------------------------------
__global__ __launch_bounds__(256) void transform_kernel(
    const float* __restrict__ pooled,
    const float* __restrict__ W,      // [128,128] row-major [out][in]
    const float* __restrict__ b,
    float* __restrict__ out, int S) {
  __shared__ float Wt[D_DIM][D_DIM + 1];  // Wt[d][j] = W[j][d]
  int t = threadIdx.x;
  for (int f = t; f < D_DIM * D_DIM; f += 256)
    Wt[f & (D_DIM - 1)][f >> 7] = W[f];
  __syncthreads();

  int lane = t & 63;
  int wv = t >> 6;
  float2 bb = *reinterpret_cast<const float2*>(&b[2 * lane]);
  int stride = gridDim.x * 4 * 2;

  for (int s0 = (blockIdx.x * 4 + wv) * 2; s0 < S; s0 += stride) {
    float2 rv0 = *reinterpret_cast<const float2*>(&pooled[(long long)s0 * D_DIM + 2 * lane]);
    bool has1 = (s0 + 1) < S;
    float2 rv1 = has1
        ? *reinterpret_cast<const float2*>(&pooled[(long long)(s0 + 1) * D_DIM + 2 * lane])
        : make_float2(0.f, 0.f);
    float o0x = bb.x, o0y = bb.y, o1x = bb.x, o1y = bb.y;
#pragma unroll
    for (int k = 0; k < 64; ++k) {
      float p00 = __shfl(rv0.x, k);
      float p01 = __shfl(rv0.y, k);
      float p10 = __shfl(rv1.x, k);
      float p11 = __shfl(rv1.y, k);
      float2 w0 = *reinterpret_cast<const float2*>(&Wt[2 * k][2 * lane]);
      float2 w1 = *reinterpret_cast<const float2*>(&Wt[2 * k + 1][2 * lane]);
      o0x += p00 * w0.x + p01 * w1.x;
      o0y += p00 * w0.y + p01 * w1.y;
      o1x += p10 * w0.x + p11 * w1.x;
      o1y += p10 * w0.y + p11 * w1.y;
    }
    *reinterpret_cast<float2*>(&out[(long long)s0 * D_DIM + 2 * lane]) =
        make_float2(o0x, o0y);
    if (has1)
      *reinterpret_cast<float2*>(&out[(long long)(s0 + 1) * D_DIM + 2 * lane]) =
          make_float2(o1x, o1y);
  }
}

extern "C" void kernel_launch(void* const* d_in, const int* in_sizes, int n_in,
                              void* d_out, int out_size, void* d_ws, size_t ws_size,
                              hipStream_t stream) {
  const float* x = (const float*)d_in[0];
  const int* idx = (const int*)d_in[1];
  const float* W = (const float*)d_in[3];
  const float* b = (const float*)d_in[4];
  float* out = (float*)d_out;

  int N = in_sizes[0] / D_DIM;
  int S = out_size / D_DIM;

  // ws layout: fill[S] | ov_count[4] | slots[S*128] | ovs[N] | ovr[N] | pooled[S*128]
  int* fill = (int*)d_ws;
  int* ov_count = fill + S;
  int* slots = fill + S + 4;
  int* ovs = slots + (long long)S * SLOT_CAP;
  int* ovr = ovs + N;
  float* pooled = (float*)(ovr + N);

  hipMemsetAsync(fill, 0, (size_t)(S + 4) * sizeof(int), stream);

  int n4 = N / 4;
  scatter_slots_kernel<<<2048, 256, 0, stream>>>((const int4*)idx, fill, slots,
                                                 ov_count, ovs, ovr, n4);
  gather_reduce_kernel<<<(S + 15) / 16, 256, 0, stream>>>(x, slots, fill,
                                                          pooled, S);
  fixup_kernel<<<256, 128, 0, stream>>>(ov_count, ovs, ovr, x, pooled);
  transform_kernel<<<2048, 256, 0, stream>>>(pooled, W, b, out, S);
}